// Round 1
// baseline (1933.586 us; speedup 1.0000x reference)
//
#include <hip/hip_runtime.h>

#define H 256
#define W 256
#define CIN 16
#define COUT 16
#define OH 254
#define OW 254
#define TW 32
#define TH 32
#define ITW 34
#define ITH 34

__device__ __forceinline__ int sdot4(int a, int b, int c) {
#if defined(__has_builtin) && __has_builtin(__builtin_amdgcn_sdot4)
    return __builtin_amdgcn_sdot4(a, b, c, false);
#else
    return c + (int)(signed char)(a       ) * (int)(signed char)(b       )
             + (int)(signed char)(a >>  8 ) * (int)(signed char)(b >>  8 )
             + (int)(signed char)(a >> 16 ) * (int)(signed char)(b >> 16 )
             + (int)(signed char)(a >> 24 ) * (int)(signed char)(b >> 24 );
#endif
}

// out[n][co][oh][ow] = 1e-4 * (sum_{cin,kh,kw} x*w - 3*sum(x) - 7*sum(w) + 3024) + bdeq[co]
__global__ __launch_bounds__(256, 2) void conv_q8_kernel(
    const int* __restrict__ x, const int* __restrict__ wq,
    const float* __restrict__ bias, float* __restrict__ out) {
    __shared__ int   lds_x[ITH * 4 * ITW];   // [(row*4 + pack)*34 + col], 4 cin bytes per int
    __shared__ int   lds_w[COUT * 9 * 4];    // [(co*9 + tap)*4 + pack]
    __shared__ int   lds_c[COUT];            // -7*sumW + 3024
    __shared__ float lds_b[COUT];            // dequantized bias

    const int tid = threadIdx.x;
    const int tow = blockIdx.x, toh = blockIdx.y, n = blockIdx.z;
    const int oh0 = toh * TH, ow0 = tow * TW;

    // ---- stage packed weights into LDS (weight tensor is tiny, L2-resident) ----
    for (int i = tid; i < COUT * 9 * 4; i += 256) {
        const int co  = i / 36;
        const int rem = i - co * 36;
        const int tap = rem >> 2;      // 0..8
        const int p   = rem & 3;       // cin pack
        const int kh  = tap / 3, kw = tap - 3 * kh;
        const int base = co * CIN * 9 + kh * 3 + kw;
        int pk = 0;
#pragma unroll
        for (int b = 0; b < 4; ++b) {
            const int v = wq[base + (p * 4 + b) * 9] & 0xff;
            pk |= v << (8 * b);
        }
        lds_w[i] = pk;
    }
    // ---- per-cout constants ----
    if (tid < COUT) {
        int s = 0;
        const int* wc = wq + tid * CIN * 9;
#pragma unroll
        for (int k = 0; k < CIN * 9; ++k) s += wc[k];
        lds_c[tid] = -7 * s + 144 * 21;
        float r = rintf(bias[tid] * 10000.0f);                 // round-half-even
        r = fminf(fmaxf(r, -2147483648.0f), 2147483647.0f);    // clamp to int32 range
        lds_b[tid] = r * 1e-4f;
    }

    // ---- stage input halo tile (16 x 34 x 34) packed to int8 in LDS ----
    const int* xn = x + (size_t)n * (CIN * H * W);
    for (int pix = tid; pix < ITH * ITW; pix += 256) {
        const int r   = pix / ITW;
        const int col = pix - r * ITW;
        const int ih = oh0 + r, iw = ow0 + col;
        const bool ok = (ih < H) && (iw < W);
        const int ihc = ok ? ih : H - 1;
        const int iwc = ok ? iw : W - 1;
        const int addr = ihc * W + iwc;
#pragma unroll
        for (int p = 0; p < 4; ++p) {
            int pk = 0;
#pragma unroll
            for (int b = 0; b < 4; ++b) {
                int v = xn[(p * 4 + b) * (H * W) + addr];
                if (!ok) v = 0;
                pk |= (v & 0xff) << (8 * b);
            }
            lds_x[(r * 4 + p) * ITW + col] = pk;
        }
    }
    __syncthreads();

    // ---- compute: each thread = 4 vertical output pixels x 16 couts ----
    const int owl = tid & 31;
    const int ohl = (tid >> 5) << 2;

    int acc[COUT][4];
    int sx[4];
#pragma unroll
    for (int co = 0; co < COUT; ++co)
#pragma unroll
        for (int j = 0; j < 4; ++j) acc[co][j] = 0;
#pragma unroll
    for (int j = 0; j < 4; ++j) sx[j] = 0;

#pragma unroll
    for (int kw = 0; kw < 3; ++kw) {
        // hoist the 6-row x 4-pack input column slice into registers
        int xp[6][4];
#pragma unroll
        for (int rr = 0; rr < 6; ++rr)
#pragma unroll
            for (int p = 0; p < 4; ++p)
                xp[rr][p] = lds_x[((ohl + rr) * 4 + p) * ITW + owl + kw];

        // row sums for the -3*sum(x) term
        int s6[6];
#pragma unroll
        for (int rr = 0; rr < 6; ++rr) {
            int s = 0;
#pragma unroll
            for (int p = 0; p < 4; ++p) s = sdot4(xp[rr][p], 0x01010101, s);
            s6[rr] = s;
        }
#pragma unroll
        for (int j = 0; j < 4; ++j) sx[j] += s6[j] + s6[j + 1] + s6[j + 2];

#pragma unroll
        for (int kh = 0; kh < 3; ++kh) {
            const int tap = kh * 3 + kw;
#pragma unroll
            for (int co = 0; co < COUT; ++co) {
                const int wb = (co * 9 + tap) * 4;
                const int w0 = lds_w[wb + 0];
                const int w1 = lds_w[wb + 1];
                const int w2 = lds_w[wb + 2];
                const int w3 = lds_w[wb + 3];
#pragma unroll
                for (int j = 0; j < 4; ++j) {
                    int a = acc[co][j];
                    a = sdot4(xp[j + kh][0], w0, a);
                    a = sdot4(xp[j + kh][1], w1, a);
                    a = sdot4(xp[j + kh][2], w2, a);
                    a = sdot4(xp[j + kh][3], w3, a);
                    acc[co][j] = a;
                }
            }
        }
    }

    // ---- epilogue ----
    const int oh_g = oh0 + ohl;
    const int ow_g = ow0 + owl;
    if (ow_g < OW) {
        float* outn = out + (size_t)n * (COUT * OH * OW);
#pragma unroll
        for (int co = 0; co < COUT; ++co) {
            const int   ci = lds_c[co];
            const float bf = lds_b[co];
#pragma unroll
            for (int j = 0; j < 4; ++j) {
                const int oh = oh_g + j;
                if (oh < OH) {
                    const int tot = acc[co][j] - 3 * sx[j] + ci;
                    outn[(co * OH + oh) * OW + ow_g] = fmaf(1e-4f, (float)tot, bf);
                }
            }
        }
    }
}

extern "C" void kernel_launch(void* const* d_in, const int* in_sizes, int n_in,
                              void* d_out, int out_size, void* d_ws, size_t ws_size,
                              hipStream_t stream) {
    const int*   x    = (const int*)d_in[0];
    const int*   wq   = (const int*)d_in[1];
    const float* bias = (const float*)d_in[2];
    float*       out  = (float*)d_out;

    const int n = in_sizes[0] / (CIN * H * W);   // 64
    dim3 grid((OW + TW - 1) / TW, (OH + TH - 1) / TH, n);
    conv_q8_kernel<<<grid, 256, 0, stream>>>(x, wq, bias, out);
}

// Round 2
// 480.487 us; speedup vs baseline: 4.0242x; 4.0242x over previous
//
#include <hip/hip_runtime.h>

#define H 256
#define W 256
#define CIN 16
#define COUT 16
#define OH 254
#define OW 254
#define OHB 12          // output rows per block
#define IRB (OHB + 2)   // 14 input rows staged
#define COLS 259        // cols 0..258 staged (240 + 15 + 3 halo for kw-dummy)
#define NOHG 22         // ceil(254 / 12)

typedef int int4v __attribute__((ext_vector_type(4)));

// out[n][co][oh][ow] = 1e-4 * (Sum x*w - 3*Sum(x) - 7*Sum(w) + 3024) + bdeq[co]
// Implicit GEMM: M=16 co, N=16 ow, K=64 = kw(4; kw==3 zero-weight) x cin(16)
// per MFMA; 3 MFMAs over kh. A-lane: m=lane&15 (co), k-chunk=lane>>4 (kw),
// bytes=cin. B-lane: n=lane&15 (ow off), k-chunk=lane>>4 (kw) -> reads the
// packed-cin 16B of pixel col ow0+(lane&15)+(lane>>4). C/D: col=lane&15,
// row=(lane>>4)*4+reg.
__global__ __launch_bounds__(256, 2) void conv_q8_mfma(
    const int* __restrict__ x, const int* __restrict__ wq,
    const float* __restrict__ bias, float* __restrict__ out)
{
    __shared__ int4v lds_x[IRB * COLS];   // [row*COLS + col], 16 cin bytes/pixel
    __shared__ int4v lds_wA[192];         // [(kh*4 + kw)*16 + co]
    __shared__ int   lds_ci[COUT];        // -7*sumW + 3024
    __shared__ float lds_bf[COUT];        // dequantized bias

    const int tid = threadIdx.x;
    const int ohg = blockIdx.x;
    const int n   = blockIdx.y;
    const int oh0 = ohg * OHB;

    // ---- stage packed A (weights) ----
    for (int t = tid; t < 192; t += 256) {
        const int co = t & 15;
        const int kw = (t >> 4) & 3;
        const int kh = t >> 6;
        int4v pk = {0, 0, 0, 0};
        if (kw < 3) {
#pragma unroll
            for (int q = 0; q < 4; ++q) {
                int r = 0;
#pragma unroll
                for (int b = 0; b < 4; ++b) {
                    const int cin = q * 4 + b;
                    r |= (wq[((co * CIN + cin) * 3 + kh) * 3 + kw] & 0xff) << (8 * b);
                }
                pk[q] = r;
            }
        }
        lds_wA[t] = pk;
    }
    // ---- per-cout constants ----
    if (tid < COUT) {
        int s = 0;
        const int* wc = wq + tid * CIN * 9;
#pragma unroll
        for (int k = 0; k < CIN * 9; ++k) s += wc[k];
        lds_ci[tid] = -7 * s + 144 * 21;
        float r = rintf(bias[tid] * 10000.0f);                // round-half-even
        r = fminf(fmaxf(r, -2147483648.0f), 2147483647.0f);   // clamp int32 range
        lds_bf[tid] = r * 1e-4f;
    }

    // ---- stage input: full-width rows, packed cin16 -> 16B per pixel ----
    const int* xn = x + (size_t)n * (CIN * H * W);
    for (int t = tid; t < IRB * COLS; t += 256) {
        const int row = t / COLS;
        const int col = t - row * COLS;
        int4v pk = {0, 0, 0, 0};
        if (col < W) {
            int ih = oh0 + row;
            if (ih > H - 1) ih = H - 1;   // clamp (rows past image are masked at store)
            const int* p = xn + ih * W + col;
#pragma unroll
            for (int q = 0; q < 4; ++q) {
                int r = 0;
#pragma unroll
                for (int b = 0; b < 4; ++b)
                    r |= (p[(q * 4 + b) * (H * W)] & 0xff) << (8 * b);
                pk[q] = r;
            }
        }
        lds_x[t] = pk;
    }
    __syncthreads();

    // ---- compute: 4 waves x 3 oh rows x 16 ow-groups of 16 ----
    const int wave = tid >> 6;
    const int lane = tid & 63;
    const int n16  = lane & 15;
    const int quad = lane >> 4;

    const int4v a0 = lds_wA[(0 * 4 + quad) * 16 + n16];
    const int4v a1 = lds_wA[(1 * 4 + quad) * 16 + n16];
    const int4v a2 = lds_wA[(2 * 4 + quad) * 16 + n16];
    const int ov = (quad < 3) ? 0x01010101 : 0;
    const int4v aones = {ov, ov, ov, ov};

    int   ci_r[4];
    float bf_r[4];
#pragma unroll
    for (int r = 0; r < 4; ++r) {
        ci_r[r] = lds_ci[quad * 4 + r];
        bf_r[r] = lds_bf[quad * 4 + r];
    }

    float* outn = out + (size_t)n * (COUT * OH * OW);
    const int coff = n16 + quad;

#pragma unroll
    for (int i = 0; i < 3; ++i) {
        const int rl = wave * 3 + i;
        const int oh = oh0 + rl;
        if (oh >= OH) continue;   // wave-uniform
        for (int g = 0; g < 16; ++g) {
            const int ow0 = g * 16;
            const int c = ow0 + coff;
            const int4v b0 = lds_x[(rl + 0) * COLS + c];
            const int4v b1 = lds_x[(rl + 1) * COLS + c];
            const int4v b2 = lds_x[(rl + 2) * COLS + c];
            int4v acc = {0, 0, 0, 0};
            int4v acs = {0, 0, 0, 0};
            acc = __builtin_amdgcn_mfma_i32_16x16x64_i8(a0, b0, acc, 0, 0, 0);
            acc = __builtin_amdgcn_mfma_i32_16x16x64_i8(a1, b1, acc, 0, 0, 0);
            acc = __builtin_amdgcn_mfma_i32_16x16x64_i8(a2, b2, acc, 0, 0, 0);
            acs = __builtin_amdgcn_mfma_i32_16x16x64_i8(aones, b0, acs, 0, 0, 0);
            acs = __builtin_amdgcn_mfma_i32_16x16x64_i8(aones, b1, acs, 0, 0, 0);
            acs = __builtin_amdgcn_mfma_i32_16x16x64_i8(aones, b2, acs, 0, 0, 0);
            const int sx = acs[0];          // all C rows identical for A=ones
            const int ow = ow0 + n16;
            if (ow < OW) {
#pragma unroll
                for (int r = 0; r < 4; ++r) {
                    const int co  = quad * 4 + r;
                    const int tot = acc[r] - 3 * sx + ci_r[r];
                    outn[(co * OH + oh) * OW + ow] = fmaf(1e-4f, (float)tot, bf_r[r]);
                }
            }
        }
    }
}

extern "C" void kernel_launch(void* const* d_in, const int* in_sizes, int n_in,
                              void* d_out, int out_size, void* d_ws, size_t ws_size,
                              hipStream_t stream) {
    const int*   x    = (const int*)d_in[0];
    const int*   wq   = (const int*)d_in[1];
    const float* bias = (const float*)d_in[2];
    float*       out  = (float*)d_out;

    const int n = in_sizes[0] / (CIN * H * W);   // 64
    dim3 grid(NOHG, n);
    conv_q8_mfma<<<grid, 256, 0, stream>>>(x, wq, bias, out);
}